// Round 17
// baseline (3337.793 us; speedup 1.0000x reference)
//
#include <hip/hip_runtime.h>
#include <hip/hip_bf16.h>
#include <math.h>

#define BATCH 128
#define LEN   64000
#define FS    256
#define STEPS 200
#define NFILT 64
#define HID   512
#define HID2  512
#define NOUT  10
#define NF    320
#define G4    2048
#define KTOT  1024
#define NBLK  256
#define HSLOT (BATCH * HID2)

typedef __bf16  bf16x8 __attribute__((ext_vector_type(8)));
typedef float   f32x4  __attribute__((ext_vector_type(4)));
typedef __hip_bfloat16 hbf;
typedef unsigned long long ull;

// gbar region word layout (stride-16 lines)
#define ARV(b)  (128 + (b) * 16)
#define REL_(i) (128 + 4096 + (i) * 16)
#define BAR_WORDS (128 + 4096 + 128)

// ---------------------------------------------------------------------------
__device__ __forceinline__ float fsig(float x) { return 1.f / (1.f + __expf(-x)); }
__device__ __forceinline__ float ftanh(float x) { return 1.f - 2.f / (__expf(2.f * x) + 1.f); }
__device__ __forceinline__ void imulf_(float al, float au, float bl, float bu,
                                       float& lo, float& hi) {
    const float p1 = al * bl, p2 = al * bu, p3 = au * bl, p4 = au * bu;
    lo = fminf(fminf(p1, p2), fminf(p3, p4));
    hi = fmaxf(fmaxf(p1, p2), fmaxf(p3, p4));
}

// ---- agent-scope ops (device-coherent point); R9/R12-proven --------------
__device__ __forceinline__ bf16x8 loadA16_agent(const hbf* p) {
    union { ull u[2]; bf16x8 v; } t;
    ull* q = (ull*)p;
    t.u[0] = __hip_atomic_load(q,     __ATOMIC_RELAXED, __HIP_MEMORY_SCOPE_AGENT);
    t.u[1] = __hip_atomic_load(q + 1, __ATOMIC_RELAXED, __HIP_MEMORY_SCOPE_AGENT);
    return t.v;
}
__device__ __forceinline__ unsigned ld_flag(const unsigned* p) {
    return __hip_atomic_load(p, __ATOMIC_RELAXED, __HIP_MEMORY_SCOPE_AGENT);
}
__device__ __forceinline__ void st_flag(unsigned* p, unsigned v) {
    __hip_atomic_store(p, v, __ATOMIC_RELAXED, __HIP_MEMORY_SCOPE_AGENT);
}
// XCD-local (TCC-executed) counter ops: workgroup-scope RMWs always run at
// the issuing XCD's L2 (L1 does no atomics) -> exact for same-XCD groups.
__device__ __forceinline__ unsigned rd_cnt_local(unsigned* p) {
    return __hip_atomic_fetch_add(p, 0u, __ATOMIC_RELAXED,
                                  __HIP_MEMORY_SCOPE_WORKGROUP);
}
__device__ __forceinline__ void bump_local(unsigned* p) {
    __hip_atomic_fetch_add(p, 1u, __ATOMIC_RELAXED,
                           __HIP_MEMORY_SCOPE_WORKGROUP);
}

// ---------------------------------------------------------------------------
// Weight prep kernels (unchanged, verified)
// ---------------------------------------------------------------------------
__global__ __launch_bounds__(256) void prep_weights_kernel(
    const float* __restrict__ wih, const float* __restrict__ whh,
    hbf* __restrict__ Wt)
{
    __shared__ float tile[32][33];
    const int n0 = blockIdx.x * 32;
    const int k0 = blockIdx.y * 32;
    const int tx = threadIdx.x & 31;
    const int ty = threadIdx.x >> 5;

    for (int r = ty; r < 32; r += 8) {
        const int k = k0 + r;
        const float* src = (k < HID) ? (wih + (size_t)k * G4)
                                     : (whh + (size_t)(k - HID) * G4);
        tile[r][tx] = src[n0 + tx];
    }
    __syncthreads();
    for (int r = ty; r < 32; r += 8) {
        const int n = n0 + r;
        Wt[(size_t)n * KTOT + k0 + tx] = __float2bfloat16(tile[tx][r]);
    }
}

__global__ __launch_bounds__(256) void prep_mtx1_kernel(
    const float* __restrict__ mtx1, hbf* __restrict__ W)
{
    __shared__ float tile[32][33];
    const int n0 = blockIdx.x * 32;
    const int k0 = blockIdx.y * 32;
    const int tx = threadIdx.x & 31;
    const int ty = threadIdx.x >> 5;

    for (int r = ty; r < 32; r += 8) {
        const int k = k0 + r;
        const int n = n0 + tx;
        tile[r][tx] = (n < FS + 2) ? mtx1[k * (FS + 2) + n] : 0.f;
    }
    __syncthreads();
    for (int r = ty; r < 32; r += 8) {
        const int n = n0 + r;
        if (n < 272)
            W[(size_t)n * 256 + k0 + tx] = __float2bfloat16(tile[tx][r]);
    }
}

__global__ __launch_bounds__(256) void prep_lin1_kernel(
    const float* __restrict__ lin1_w, hbf* __restrict__ W)
{
    __shared__ float tile[32][33];
    const int n0 = blockIdx.x * 32;
    const int k0 = blockIdx.y * 32;
    const int tx = threadIdx.x & 31;
    const int ty = threadIdx.x >> 5;

    for (int r = ty; r < 32; r += 8)
        tile[r][tx] = lin1_w[(size_t)(k0 + r) * HID + n0 + tx];
    __syncthreads();
    for (int r = ty; r < 32; r += 8)
        W[(size_t)(n0 + r) * 64 + k0 + tx] = __float2bfloat16(tile[tx][r]);
}

// ---------------------------------------------------------------------------
// Frontend v3 (unchanged, verified R15)
// ---------------------------------------------------------------------------
#define FB_A1C  0
#define FB_A1R  8704
#define FB_O1C  17408
#define FB_O1R  34816
#define FB_S3C  52224
#define FB_S3R  54272
#define FB_SIZE 56320

__global__ __launch_bounds__(512) void frontend3_kernel(
    const float* __restrict__ lb, const float* __restrict__ ub,
    const hbf* __restrict__ Wt1f,
    const float* __restrict__ mtx2,
    const hbf* __restrict__ Wt3f,
    const float* __restrict__ lin1_b,
    hbf* __restrict__ Xc, hbf* __restrict__ Xr)
{
    __shared__ char fbuf[FB_SIZE];
    hbf*   A1c = (hbf*)(fbuf + FB_A1C);
    hbf*   A1r = (hbf*)(fbuf + FB_A1R);
    float* o1C = (float*)(fbuf + FB_O1C);
    float* o1R = (float*)(fbuf + FB_O1R);
    hbf*   SQL = A1c;
    hbf*   SQU = A1r;
    hbf*   s3c = (hbf*)(fbuf + FB_S3C);
    hbf*   s3r = (hbf*)(fbuf + FB_S3R);

    const int tid  = threadIdx.x;
    const int row0 = blockIdx.x * 16;
    const int b    = row0 / NF;
    const int f0   = row0 % NF;

    for (int c = tid; c < 16 * 256; c += 512) {
        const int m = c >> 8, i = c & 255;
        const int pos = (f0 + m) * STEPS + i;
        float l = 0.f, u = 0.f;
        if (pos < LEN) {
            l = lb[(size_t)b * LEN + pos];
            u = ub[(size_t)b * LEN + pos];
        }
        A1c[m * 272 + i] = __float2bfloat16(0.5f * (l + u));
        A1r[m * 272 + i] = __float2bfloat16(0.5f * (u - l));
    }
    __syncthreads();

    {
        const int w    = tid >> 6;
        const int lane = tid & 63;
        const int op   = w & 1;
        const int nh   = w >> 1;
        const int rc   = lane & 15;
        const int gk   = lane >> 4;
        const unsigned amask = op ? 0x7FFF7FFFu : 0xFFFFFFFFu;
        const hbf* ap = (op ? A1r : A1c) + rc * 272 + 8 * gk;
        float* outp = op ? o1R : o1C;
        const int nt0 = nh * 4, nt1 = (nh == 3) ? 17 : nh * 4 + 4;

        for (int nt = nt0; nt < nt1; ++nt) {
            f32x4 acc = {0.f, 0.f, 0.f, 0.f};
            const hbf* bp = Wt1f + (size_t)(nt * 16 + rc) * 256 + 8 * gk;
#pragma unroll
            for (int k0 = 0; k0 < 256; k0 += 32) {
                const bf16x8 afr = *(const bf16x8*)(ap + k0);
                union { bf16x8 v; unsigned u[4]; } t2;
                t2.v = *(const bf16x8*)(bp + k0);
                t2.u[0] &= amask; t2.u[1] &= amask;
                t2.u[2] &= amask; t2.u[3] &= amask;
                acc = __builtin_amdgcn_mfma_f32_16x16x32_bf16(afr, t2.v, acc, 0, 0, 0);
            }
            const int n = nt * 16 + rc;
#pragma unroll
            for (int reg = 0; reg < 4; ++reg)
                outp[(4 * gk + reg) * 272 + n] = acc[reg];
        }
    }
    __syncthreads();

    for (int c = tid; c < 16 * 258; c += 512) {
        const int m = c / 258, n = c - m * 258;
        const float oc = o1C[m * 272 + n];
        const float orr = o1R[m * 272 + n];
        const float l1l = oc - orr, l1u = oc + orr;
        const float a = l1l * l1l, bb = l1u * l1u;
        const float squ = fmaxf(a, bb);
        const float sql = (l1l <= 0.f && l1u >= 0.f) ? 0.f : fminf(a, bb);
        SQL[m * 272 + n] = __float2bfloat16(sql);
        SQU[m * 272 + n] = __float2bfloat16(squ);
    }
    __syncthreads();

    for (int idx = tid; idx < 16 * 64; idx += 512) {
        const int m = idx >> 6, n = idx & 63;
        float l2l = 1e-10f, l2u = 1e-10f;
#pragma unroll 2
        for (int i = 0; i < 258; ++i) {
            const float w = mtx2[i * NFILT + n];
            l2l = fmaf(__bfloat162float(SQL[m * 272 + i]), w, l2l);
            l2u = fmaf(__bfloat162float(SQU[m * 272 + i]), w, l2u);
        }
        const float lgl = logf(l2l);
        const float lgu = logf(l2u);
        s3c[m * 64 + n] = __float2bfloat16(0.5f * (lgl + lgu));
        s3r[m * 64 + n] = __float2bfloat16(0.5f * (lgu - lgl));
    }
    __syncthreads();

    {
        const int w    = tid >> 6;
        const int lane = tid & 63;
        const int rc   = lane & 15;
        const int gk   = lane >> 4;
        const hbf* apc = s3c + rc * 64 + 8 * gk;
        const hbf* apr = s3r + rc * 64 + 8 * gk;

        for (int nt = w * 4; nt < w * 4 + 4; ++nt) {
            f32x4 accC = {0.f, 0.f, 0.f, 0.f};
            f32x4 accR = {0.f, 0.f, 0.f, 0.f};
            const hbf* bp = Wt3f + (size_t)(nt * 16 + rc) * 64 + 8 * gk;
#pragma unroll
            for (int k0 = 0; k0 < 64; k0 += 32) {
                const bf16x8 ac = *(const bf16x8*)(apc + k0);
                const bf16x8 ar = *(const bf16x8*)(apr + k0);
                union { bf16x8 v; unsigned u[4]; } tw, ta;
                tw.v = *(const bf16x8*)(bp + k0);
                ta.v = tw.v;
                ta.u[0] &= 0x7FFF7FFFu; ta.u[1] &= 0x7FFF7FFFu;
                ta.u[2] &= 0x7FFF7FFFu; ta.u[3] &= 0x7FFF7FFFu;
                accC = __builtin_amdgcn_mfma_f32_16x16x32_bf16(ac, tw.v, accC, 0, 0, 0);
                accR = __builtin_amdgcn_mfma_f32_16x16x32_bf16(ar, ta.v, accR, 0, 0, 0);
            }
            const int n = nt * 16 + rc;
            const float bn = lin1_b[n];
#pragma unroll
            for (int reg = 0; reg < 4; ++reg) {
                const int m = 4 * gk + reg;
                const float oc = accC[reg] + bn;
                const float orr = accR[reg];
                const float n1l = oc - orr, n1u = oc + orr;
                const float rl = fmaxf(n1l, 0.f), ru = fmaxf(n1u, 0.f);
                const size_t o = ((size_t)(f0 + m) * BATCH + b) * HID + n;
                Xc[o] = __float2bfloat16(0.5f * (rl + ru));
                Xr[o] = __float2bfloat16(0.5f * (ru - rl));
            }
        }
    }
}

// ---------------------------------------------------------------------------
// One-time global barrier for registration (R7-proven).
// ---------------------------------------------------------------------------
__device__ __forceinline__ void gbar(unsigned* bar, unsigned gen,
                                     int bid, int tid) {
    __builtin_amdgcn_s_waitcnt(0);
    __syncthreads();
    if (bid == 0) {
        if (tid != 0) {
            while (ld_flag(&bar[ARV(tid)]) < gen)
                __builtin_amdgcn_s_sleep(1);
        }
        __syncthreads();
        if (tid < 8) st_flag(&bar[REL_(tid)], gen);
    } else {
        if (tid == 0) {
            st_flag(&bar[ARV(bid)], gen);
            while (ld_flag(&bar[REL_(bid & 7)]) < gen)
                __builtin_amdgcn_s_sleep(4);
        }
        asm volatile("" ::: "memory");
    }
    __syncthreads();
}

// ---------------------------------------------------------------------------
__device__ __forceinline__ void cell_elem(
    const float C[4], const float R[4], const float bs[4],
    float& cl_r, float& cu_r, float& nhl, float& nhu)
{
    float gl[4], gu[4];
#pragma unroll
    for (int g = 0; g < 4; ++g) {
        gl[g] = C[g] - R[g] + bs[g];
        gu[g] = C[g] + R[g] + bs[g];
    }
    const float il = fsig(gl[0]), iu = fsig(gu[0]);
    const float fl = fsig(gl[1]), fu = fsig(gu[1]);
    const float ggl = ftanh(gl[2]), ggu = ftanh(gu[2]);
    const float ol = fsig(gl[3]), ou = fsig(gu[3]);

    float fcl, fcu, igl, igu;
    imulf_(fl, fu, cl_r, cu_r, fcl, fcu);
    imulf_(il, iu, ggl, ggu, igl, igu);
    const float ncl = fcl + igl, ncu = fcu + igu;
    cl_r = ncl; cu_r = ncu;
    imulf_(ol, ou, ftanh(ncl), ftanh(ncu), nhl, nhu);
}

// GEMM over one K-half from LDS weights; MASKED is a literal 0/1.
#define GEMM_HALF(KBASE, MASKED)                                               \
    _Pragma("unroll")                                                          \
    for (int kk = 0; kk < 16; ++kk) {                                          \
        const int KK = (KBASE) + kk;                                           \
        _Pragma("unroll")                                                      \
        for (int g = 0; g < 4; ++g) {                                          \
            union { bf16x8 v; unsigned u[4]; } t2;                             \
            t2.v = *(const bf16x8*)&Wlds[(size_t)(((g << 5) | KK) * 64 + lane) * 8]; \
            if (MASKED) {                                                      \
                t2.u[0] &= 0x7FFF7FFFu; t2.u[1] &= 0x7FFF7FFFu;                \
                t2.u[2] &= 0x7FFF7FFFu; t2.u[3] &= 0x7FFF7FFFu;                \
            }                                                                  \
            acc[g] = __builtin_amdgcn_mfma_f32_16x16x32_bf16(af[kk], t2.v, acc[g], 0, 0, 0); \
        }                                                                      \
    }

#define LOADA16(PTR)                                                           \
    _Pragma("unroll")                                                          \
    for (int i = 0; i < 16; ++i) af[i] = *(const bf16x8*)((PTR) + 32 * i);

// own-group poll: XCD-local counter fast path with agent-counter fallback
#define POLL_OWN(GID, TGT)                                                     \
    if (tid == 0) {                                                            \
        unsigned* lp = &lcnt[(GID) * 16];                                      \
        const unsigned* gp = &gcnt[(GID) * 16];                                \
        int spins = 0;                                                         \
        for (;;) {                                                             \
            if ((int)rd_cnt_local(lp) >= (TGT)) break;                         \
            if (((++spins) & 15) == 0 && (int)ld_flag(gp) >= (TGT)) break;     \
            __builtin_amdgcn_s_sleep(1);                                       \
        }                                                                      \
    }                                                                          \
    __syncthreads();

// cross-group poll: agent counter only
#define POLL_CROSS(GID, TGT)                                                   \
    if (tid == 0) {                                                            \
        const unsigned* pp = &gcnt[(GID) * 16];                                \
        while ((int)ld_flag(pp) < (TGT)) __builtin_amdgcn_s_sleep(1);          \
    }                                                                          \
    __syncthreads();

// ---------------------------------------------------------------------------
// Persistent LSTM. Fast path (group == one physical XCD): intra-group H via
// plain L2 stores/loads; own-group sync via XCD-local L2 atomics (agent
// fallback); L0's agent Ring0 publication DEFERRED one step so its coherent-
// point drain overlaps the whole step (L1 lag +1). Slow path: R12 protocol.
// ---------------------------------------------------------------------------
__global__ __launch_bounds__(256, 1) void lstm_persistent(
    const hbf* Xc, const hbf* Xr,                       // aliased w/ Ring1
    hbf* Ring1C, hbf* Ring1R,                           // = Xc, Xr (fast path)
    const hbf* __restrict__ Wt0, const hbf* __restrict__ Wt1,
    const float* __restrict__ b0, const float* __restrict__ b1,
    hbf* __restrict__ Ring0C, hbf* __restrict__ Ring0R, // NF slots, agent
    hbf* __restrict__ RP0C, hbf* __restrict__ RP0R,     // NF slots, plain (may==Ring0)
    int useP0,
    const hbf* __restrict__ Zbuf,                       // HSLOT zeros
    hbf* __restrict__ H1c0, hbf* __restrict__ H1r0,
    hbf* __restrict__ H1c1, hbf* __restrict__ H1r1,
    float* __restrict__ h1l, float* __restrict__ h1u,
    unsigned* __restrict__ bar, unsigned* __restrict__ tkt,
    unsigned* __restrict__ gcnt, unsigned* __restrict__ lcnt)
{
    const int tid = threadIdx.x;
    const int bid = blockIdx.x;

    __shared__ unsigned s_info, s_map;
    __shared__ int s_fast;
    __shared__ hbf   Wlds[4 * 32 * 64 * 8];      // 128 KB
    __shared__ float red[2][2][4][64][4];        // 16 KB
    __shared__ unsigned short houtC[32][16], houtR[32][16];   // 2 KB

    // ---- registration: physical XCD + ticket ----
    if (tid == 0) {
        unsigned xcc;
        asm volatile("s_getreg_b32 %0, hwreg(HW_REG_XCC_ID)" : "=s"(xcc));
        xcc &= 7u;
        const unsigned slot = __hip_atomic_fetch_add(
            &tkt[xcc * 16], 1u, __ATOMIC_RELAXED, __HIP_MEMORY_SCOPE_AGENT);
        s_info = (xcc << 16) | slot;
    }
    gbar(bar, 1, bid, tid);
    if (tid == 0) {
        unsigned cnt[8]; bool ok = true;
        for (int y = 0; y < 8; ++y) {
            cnt[y] = ld_flag(&tkt[y * 16]);
            ok = ok && (cnt[y] == 32u);
        }
        const unsigned xcc = s_info >> 16, slot = s_info & 0xffffu;
        unsigned rank;
        if (ok) rank = xcc * 32u + slot;
        else { rank = slot; for (unsigned y = 0; y < xcc; ++y) rank += cnt[y]; }
        s_map = rank; s_fast = ok ? 1 : 0;
    }
    __syncthreads();

    const unsigned rank = s_map;
    const bool fast = (s_fast != 0);
    int layer, mgrp, jslot;
    if (fast) { layer = (rank >> 5) & 1; mgrp = rank >> 6; jslot = rank & 31; }
    else      { layer = rank >> 7; mgrp = (rank >> 5) & 3; jslot = rank & 31; }
    const int m0 = mgrp * 32;
    const int j0 = jslot * 16;
    const int gid  = layer * 4 + mgrp;       // own group counter
    const int pgid = mgrp;                   // partner L0 group counter
    const bool p0 = fast && (useP0 != 0);    // defer mode

    // ---- stage weight slice into LDS ----
    {
        const hbf* Wt = layer ? Wt1 : Wt0;
        for (int c = tid; c < 8192; c += 256) {
            const int g  = c >> 11;
            const int kk = (c >> 6) & 31;
            const int l6 = c & 63;
            const int n  = g * HID2 + j0 + (l6 & 15);
            const int k  = kk * 32 + (l6 >> 4) * 8;
            *(ulonglong2*)&Wlds[(size_t)c * 8] =
                *(const ulonglong2*)(Wt + (size_t)n * KTOT + k);
        }
    }

    const int w    = tid >> 6;
    const int lane = tid & 63;
    const int op   = w & 1;                  // 0 center, 1 radius
    const int mh   = w >> 1;                 // m-half
    const int rc   = lane & 15;
    const int gk   = lane >> 4;
    const int aoff = (m0 + mh * 16 + rc) * 512 + 8 * gk;

    hbf* H1cb[2] = { H1c0, H1c1 };
    hbf* H1rb[2] = { H1r0, H1r1 };

    // cell-phase constants
    const int mm  = tid >> 4;
    const int cj  = tid & 15;
    const int ll  = ((mm >> 2) << 4) | cj;
    const int rr  = mm & 3;
    const int idx0 = (m0 + mm) * HID2 + j0 + cj;
    const int idx1 = idx0 + 16 * HID2;
    const float* bias = layer ? b1 : b0;
    float bs[4];
#pragma unroll
    for (int g = 0; g < 4; ++g) bs[g] = bias[g * HID2 + j0 + cj];

    // coalesced-store constants (1 qword per thread)
    const int st_arr = tid >> 7;             // 0=C, 1=R
    const int st_row = (tid >> 2) & 31;
    const int st_q   = tid & 3;
    const size_t st_off = (size_t)(m0 + st_row) * 512 + j0 + st_q * 4;

    float cAl = 0.f, cAu = 0.f, cBl = 0.f, cBu = 0.f;

    __syncthreads();                         // Wlds ready

    // ---- L0: prologue X[0] prefetch into registers ----
    bf16x8 xf[16];
    if (layer == 0) {
        const hbf* p = (op ? Xr : Xc) + aoff;
        bf16x8* af = xf;
        LOADA16(p)
    }

    for (int t = 0; t < NF; ++t) {
        const int wslot = t & 1, rslot = wslot ^ 1;
        f32x4 acc[4] = {f32x4{0,0,0,0}, f32x4{0,0,0,0},
                        f32x4{0,0,0,0}, f32x4{0,0,0,0}};

        if (layer == 0) {
            // deferred agent publication of Ring0[t-1] (fast+P0): values are
            // still staged in LDS from step t-1; drain overlaps this step.
            if (p0 && t > 0) {
                const ull v = *(const ull*)
                    &(st_arr ? houtR : houtC)[st_row][st_q * 4];
                hbf* aC = Ring0C + (size_t)(t - 1) * HSLOT;
                hbf* aR = Ring0R + (size_t)(t - 1) * HSLOT;
                __hip_atomic_store((ull*)((st_arr ? aR : aC) + st_off), v,
                                   __ATOMIC_RELAXED, __HIP_MEMORY_SCOPE_AGENT);
            }
            // x-half on prefetched registers, then issue X[t+1] loads
            {
                bf16x8* af = xf;
                if (op) { GEMM_HALF(0, 1) } else { GEMM_HALF(0, 0) }
                const int tn = (t + 1 < NF) ? (t + 1) : t;
                const hbf* p = (op ? Xr : Xc) + (size_t)tn * HSLOT + aoff;
                LOADA16(p)
            }
            POLL_OWN(gid, 32 * t)
            // h-half: RP0[t-1] plain (L2-hit) in fast+P0, else Ring0[t-1]
            {
                const hbf* p;
                if (t == 0)       p = Zbuf + aoff;
                else if (p0)      p = (op ? RP0R : RP0C) + (size_t)(t - 1) * HSLOT + aoff;
                else              p = (op ? Ring0R : Ring0C) + (size_t)(t - 1) * HSLOT + aoff;
                bf16x8 af[16];
                LOADA16(p)
                if (op) { GEMM_HALF(16, 1) } else { GEMM_HALF(16, 0) }
            }
        } else {
            POLL_OWN(gid, 32 * t)
            // h-half on own H-ring — overlaps the wait on L0
            {
                bf16x8 af[16];
                if (fast) {
                    const hbf* p = (t == 0) ? (Zbuf + aoff)
                        : ((op ? (const hbf*)Ring1R : (const hbf*)Ring1C)
                           + (size_t)(t - 1) * HSLOT + aoff);
                    LOADA16(p)
                } else {
                    const hbf* p = (op ? H1rb[rslot] : H1cb[rslot]) + aoff;
#pragma unroll
                    for (int i = 0; i < 16; ++i) af[i] = loadA16_agent(p + 32 * i);
                }
                if (op) { GEMM_HALF(16, 1) } else { GEMM_HALF(16, 0) }
            }
            POLL_CROSS(pgid, 32 * (t + (p0 ? 2 : 1)))
            // x-half on Ring0[t] — plain cached (fresh address)
            {
                const hbf* p = (op ? Ring0R : Ring0C) + (size_t)t * HSLOT + aoff;
                bf16x8 af[16];
                LOADA16(p)
                if (op) { GEMM_HALF(0, 1) } else { GEMM_HALF(0, 0) }
            }
        }

        // ---- reduce C/R across waves via LDS ----
#pragma unroll
        for (int g = 0; g < 4; ++g)
            *((f32x4*)&red[op][mh][g][lane][0]) = acc[g];
        __syncthreads();

        // ---- cell: 2 elements per thread, stage into LDS ----
        {
            float C0[4], R0[4], C1[4], R1[4];
#pragma unroll
            for (int g = 0; g < 4; ++g) {
                C0[g] = red[0][0][g][ll][rr];
                R0[g] = red[1][0][g][ll][rr];
                C1[g] = red[0][1][g][ll][rr];
                R1[g] = red[1][1][g][ll][rr];
            }
            const bool writeF = (layer == 1) && (t == NF - 1);

            float nhl, nhu;
            cell_elem(C0, R0, bs, cAl, cAu, nhl, nhu);
            {
                const __hip_bfloat16 hc = __float2bfloat16(0.5f * (nhl + nhu));
                const __hip_bfloat16 hr = __float2bfloat16(0.5f * (nhu - nhl));
                houtC[mm][cj] = *(const unsigned short*)&hc;
                houtR[mm][cj] = *(const unsigned short*)&hr;
            }
            if (writeF) { h1l[idx0] = nhl; h1u[idx0] = nhu; }

            cell_elem(C1, R1, bs, cBl, cBu, nhl, nhu);
            {
                const __hip_bfloat16 hc = __float2bfloat16(0.5f * (nhl + nhu));
                const __hip_bfloat16 hr = __float2bfloat16(0.5f * (nhu - nhl));
                houtC[mm + 16][cj] = *(const unsigned short*)&hc;
                houtR[mm + 16][cj] = *(const unsigned short*)&hr;
            }
            if (writeF) { h1l[idx1] = nhl; h1u[idx1] = nhu; }
        }
        __syncthreads();

        // ---- publication: u64 per thread ----
        {
            const ull v = *(const ull*)
                &(st_arr ? houtR : houtC)[st_row][st_q * 4];
            if (layer == 0) {
                if (p0) {
                    // plain store into RP0 only (agent Ring0 deferred)
                    hbf* pC = RP0C + (size_t)t * HSLOT;
                    hbf* pR = RP0R + (size_t)t * HSLOT;
                    *(ull*)((st_arr ? pR : pC) + st_off) = v;
                } else {
                    hbf* aC = Ring0C + (size_t)t * HSLOT;
                    hbf* aR = Ring0R + (size_t)t * HSLOT;
                    __hip_atomic_store((ull*)((st_arr ? aR : aC) + st_off), v,
                                       __ATOMIC_RELAXED, __HIP_MEMORY_SCOPE_AGENT);
                }
            } else if (fast) {
                hbf* pC = Ring1C + (size_t)t * HSLOT;
                hbf* pR = Ring1R + (size_t)t * HSLOT;
                *(ull*)((st_arr ? pR : pC) + st_off) = v;   // plain, same-XCD L2
            } else {
                hbf* dC = H1cb[wslot];
                hbf* dR = H1rb[wslot];
                __hip_atomic_store((ull*)((st_arr ? dR : dC) + st_off), v,
                                   __ATOMIC_RELAXED, __HIP_MEMORY_SCOPE_AGENT);
            }
        }

        // ---- arrive: drain, bump local then agent counter ----
        __builtin_amdgcn_s_waitcnt(0);
        __syncthreads();
        if (tid == 0) {
            bump_local(&lcnt[gid * 16]);
            __hip_atomic_fetch_add(&gcnt[gid * 16], 1u, __ATOMIC_RELAXED,
                                   __HIP_MEMORY_SCOPE_AGENT);
        }
    }

    // ---- L0 epilogue (defer mode): publish Ring0[NF-1], extra bump ----
    if (layer == 0 && p0) {
        const ull v = *(const ull*)
            &(st_arr ? houtR : houtC)[st_row][st_q * 4];
        hbf* aC = Ring0C + (size_t)(NF - 1) * HSLOT;
        hbf* aR = Ring0R + (size_t)(NF - 1) * HSLOT;
        __hip_atomic_store((ull*)((st_arr ? aR : aC) + st_off), v,
                           __ATOMIC_RELAXED, __HIP_MEMORY_SCOPE_AGENT);
        __builtin_amdgcn_s_waitcnt(0);
        __syncthreads();
        if (tid == 0)
            __hip_atomic_fetch_add(&gcnt[gid * 16], 1u, __ATOMIC_RELAXED,
                                   __HIP_MEMORY_SCOPE_AGENT);
    }
}

// ---------------------------------------------------------------------------
__global__ __launch_bounds__(64) void final_kernel(
    const float* __restrict__ h1l, const float* __restrict__ h1u,
    const float* __restrict__ w, const float* __restrict__ bias,
    float* __restrict__ out)
{
    const int b = blockIdx.x;
    const int j = threadIdx.x;
    if (j < NOUT) {
        float oc = bias[j], orr = 0.f;
        for (int i = 0; i < HID2; ++i) {
            const float lo = h1l[(size_t)b * HID2 + i];
            const float hi = h1u[(size_t)b * HID2 + i];
            const float wv = w[i * NOUT + j];
            oc  = fmaf(0.5f * (lo + hi), wv, oc);
            orr = fmaf(0.5f * (hi - lo), fabsf(wv), orr);
        }
        out[b * NOUT + j] = oc - orr;
        out[BATCH * NOUT + b * NOUT + j] = oc + orr;
    }
}

// ---------------------------------------------------------------------------
extern "C" void kernel_launch(void* const* d_in, const int* in_sizes, int n_in,
                              void* d_out, int out_size, void* d_ws, size_t ws_size,
                              hipStream_t stream)
{
    const float* input_lb = (const float*)d_in[0];
    const float* input_ub = (const float*)d_in[1];
    const float* mtx1     = (const float*)d_in[2];
    const float* mtx2     = (const float*)d_in[3];
    const float* lin1_w   = (const float*)d_in[4];
    const float* lin1_b   = (const float*)d_in[5];
    const float* w_ih0    = (const float*)d_in[6];
    const float* w_hh0    = (const float*)d_in[7];
    const float* b0       = (const float*)d_in[8];
    const float* w_ih1    = (const float*)d_in[9];
    const float* w_hh1    = (const float*)d_in[10];
    const float* b1       = (const float*)d_in[11];
    const float* lin2_w   = (const float*)d_in[12];
    const float* lin2_b   = (const float*)d_in[13];
    float* out = (float*)d_out;

    char* ws = (char*)d_ws;
    size_t off = 0;
    hbf* Xc = (hbf*)(ws + off); off += (size_t)NF * HSLOT * 2;
    hbf* Xr = (hbf*)(ws + off); off += (size_t)NF * HSLOT * 2;
    hbf* Wt0 = (hbf*)(ws + off); off += (size_t)G4 * KTOT * 2;
    hbf* Wt1 = (hbf*)(ws + off); off += (size_t)G4 * KTOT * 2;
    hbf* Wt1f = (hbf*)(ws + off); off += (size_t)272 * 256 * 2;
    hbf* Wt3f = (hbf*)(ws + off); off += (size_t)512 * 64 * 2;
    hbf* Ring0C = (hbf*)(ws + off); off += (size_t)NF * HSLOT * 2;
    hbf* Ring0R = (hbf*)(ws + off); off += (size_t)NF * HSLOT * 2;

    // zeroed-every-launch region
    char* zbase = ws + off;
    hbf* Zbuf = (hbf*)(ws + off); off += (size_t)HSLOT * 2;
    hbf* H1c0 = (hbf*)(ws + off); off += (size_t)HSLOT * 2;
    hbf* H1r0 = (hbf*)(ws + off); off += (size_t)HSLOT * 2;
    hbf* H1c1 = (hbf*)(ws + off); off += (size_t)HSLOT * 2;
    hbf* H1r1 = (hbf*)(ws + off); off += (size_t)HSLOT * 2;
    unsigned* tkt  = (unsigned*)(ws + off); off += (size_t)8 * 16 * 4;
    unsigned* bar  = (unsigned*)(ws + off); off += (size_t)BAR_WORDS * 4;
    unsigned* gcnt = (unsigned*)(ws + off); off += (size_t)8 * 16 * 4;
    unsigned* lcnt = (unsigned*)(ws + off); off += (size_t)8 * 16 * 4;
    const size_t zbytes = (size_t)((ws + off) - zbase);
    float* h1l = (float*)(ws + off); off += (size_t)HSLOT * 4;
    float* h1u = (float*)(ws + off); off += (size_t)HSLOT * 4;

    // optional plain mirror ring for L0 (fast path) — only if ws has room
    hbf* RP0C = Ring0C;
    hbf* RP0R = Ring0R;
    int useP0 = 0;
    {
        const size_t need = (size_t)NF * HSLOT * 2 * 2;   // two rings
        if (off + need <= ws_size) {
            RP0C = (hbf*)(ws + off); off += (size_t)NF * HSLOT * 2;
            RP0R = (hbf*)(ws + off); off += (size_t)NF * HSLOT * 2;
            useP0 = 1;
        }
    }

    hipMemsetAsync(zbase, 0, zbytes, stream);

    {
        const dim3 pgrid(G4 / 32, KTOT / 32);
        prep_weights_kernel<<<pgrid, 256, 0, stream>>>(w_ih0, w_hh0, Wt0);
        prep_weights_kernel<<<pgrid, 256, 0, stream>>>(w_ih1, w_hh1, Wt1);
        prep_mtx1_kernel<<<dim3(9, 8), 256, 0, stream>>>(mtx1, Wt1f);
        prep_lin1_kernel<<<dim3(16, 2), 256, 0, stream>>>(lin1_w, Wt3f);
    }

    frontend3_kernel<<<(BATCH * NF) / 16, 512, 0, stream>>>(
        input_lb, input_ub, Wt1f, mtx2, Wt3f, lin1_b, Xc, Xr);

    lstm_persistent<<<NBLK, 256, 0, stream>>>(
        Xc, Xr, Xc, Xr, Wt0, Wt1, b0, b1,
        Ring0C, Ring0R, RP0C, RP0R, useP0, Zbuf,
        H1c0, H1r0, H1c1, H1r1,
        h1l, h1u, bar, tkt, gcnt, lcnt);

    final_kernel<<<BATCH, 64, 0, stream>>>(h1l, h1u, lin2_w, lin2_b, out);
}

// Round 18
// 2791.678 us; speedup vs baseline: 1.1956x; 1.1956x over previous
//
#include <hip/hip_runtime.h>
#include <hip/hip_bf16.h>
#include <math.h>

#define BATCH 128
#define LEN   64000
#define FS    256
#define STEPS 200
#define NFILT 64
#define HID   512
#define HID2  512
#define NOUT  10
#define NF    320
#define G4    2048
#define KTOT  1024
#define NBLK  256
#define HSLOT (BATCH * HID2)

typedef __bf16  bf16x8 __attribute__((ext_vector_type(8)));
typedef float   f32x4  __attribute__((ext_vector_type(4)));
typedef __hip_bfloat16 hbf;
typedef unsigned long long ull;

// gbar region word layout (stride-16 lines)
#define ARV(b)  (128 + (b) * 16)
#define REL_(i) (128 + 4096 + (i) * 16)
#define BAR_WORDS (128 + 4096 + 128)

// ---------------------------------------------------------------------------
__device__ __forceinline__ float fsig(float x) { return 1.f / (1.f + __expf(-x)); }
__device__ __forceinline__ float ftanh(float x) { return 1.f - 2.f / (__expf(2.f * x) + 1.f); }
__device__ __forceinline__ void imulf_(float al, float au, float bl, float bu,
                                       float& lo, float& hi) {
    const float p1 = al * bl, p2 = al * bu, p3 = au * bl, p4 = au * bu;
    lo = fminf(fminf(p1, p2), fminf(p3, p4));
    hi = fmaxf(fmaxf(p1, p2), fmaxf(p3, p4));
}

// ---- agent-scope ops (device-coherent point); R9/R12-proven --------------
__device__ __forceinline__ bf16x8 loadA16_agent(const hbf* p) {
    union { ull u[2]; bf16x8 v; } t;
    ull* q = (ull*)p;
    t.u[0] = __hip_atomic_load(q,     __ATOMIC_RELAXED, __HIP_MEMORY_SCOPE_AGENT);
    t.u[1] = __hip_atomic_load(q + 1, __ATOMIC_RELAXED, __HIP_MEMORY_SCOPE_AGENT);
    return t.v;
}
__device__ __forceinline__ unsigned ld_flag(const unsigned* p) {
    return __hip_atomic_load(p, __ATOMIC_RELAXED, __HIP_MEMORY_SCOPE_AGENT);
}
__device__ __forceinline__ void st_flag(unsigned* p, unsigned v) {
    __hip_atomic_store(p, v, __ATOMIC_RELAXED, __HIP_MEMORY_SCOPE_AGENT);
}

// ---------------------------------------------------------------------------
// Weight prep kernels (unchanged, verified)
// ---------------------------------------------------------------------------
__global__ __launch_bounds__(256) void prep_weights_kernel(
    const float* __restrict__ wih, const float* __restrict__ whh,
    hbf* __restrict__ Wt)
{
    __shared__ float tile[32][33];
    const int n0 = blockIdx.x * 32;
    const int k0 = blockIdx.y * 32;
    const int tx = threadIdx.x & 31;
    const int ty = threadIdx.x >> 5;

    for (int r = ty; r < 32; r += 8) {
        const int k = k0 + r;
        const float* src = (k < HID) ? (wih + (size_t)k * G4)
                                     : (whh + (size_t)(k - HID) * G4);
        tile[r][tx] = src[n0 + tx];
    }
    __syncthreads();
    for (int r = ty; r < 32; r += 8) {
        const int n = n0 + r;
        Wt[(size_t)n * KTOT + k0 + tx] = __float2bfloat16(tile[tx][r]);
    }
}

__global__ __launch_bounds__(256) void prep_mtx1_kernel(
    const float* __restrict__ mtx1, hbf* __restrict__ W)
{
    __shared__ float tile[32][33];
    const int n0 = blockIdx.x * 32;
    const int k0 = blockIdx.y * 32;
    const int tx = threadIdx.x & 31;
    const int ty = threadIdx.x >> 5;

    for (int r = ty; r < 32; r += 8) {
        const int k = k0 + r;
        const int n = n0 + tx;
        tile[r][tx] = (n < FS + 2) ? mtx1[k * (FS + 2) + n] : 0.f;
    }
    __syncthreads();
    for (int r = ty; r < 32; r += 8) {
        const int n = n0 + r;
        if (n < 272)
            W[(size_t)n * 256 + k0 + tx] = __float2bfloat16(tile[tx][r]);
    }
}

__global__ __launch_bounds__(256) void prep_lin1_kernel(
    const float* __restrict__ lin1_w, hbf* __restrict__ W)
{
    __shared__ float tile[32][33];
    const int n0 = blockIdx.x * 32;
    const int k0 = blockIdx.y * 32;
    const int tx = threadIdx.x & 31;
    const int ty = threadIdx.x >> 5;

    for (int r = ty; r < 32; r += 8)
        tile[r][tx] = lin1_w[(size_t)(k0 + r) * HID + n0 + tx];
    __syncthreads();
    for (int r = ty; r < 32; r += 8)
        W[(size_t)(n0 + r) * 64 + k0 + tx] = __float2bfloat16(tile[tx][r]);
}

// ---------------------------------------------------------------------------
// Frontend v3 (unchanged, verified R15)
// ---------------------------------------------------------------------------
#define FB_A1C  0
#define FB_A1R  8704
#define FB_O1C  17408
#define FB_O1R  34816
#define FB_S3C  52224
#define FB_S3R  54272
#define FB_SIZE 56320

__global__ __launch_bounds__(512) void frontend3_kernel(
    const float* __restrict__ lb, const float* __restrict__ ub,
    const hbf* __restrict__ Wt1f,
    const float* __restrict__ mtx2,
    const hbf* __restrict__ Wt3f,
    const float* __restrict__ lin1_b,
    hbf* __restrict__ Xc, hbf* __restrict__ Xr)
{
    __shared__ char fbuf[FB_SIZE];
    hbf*   A1c = (hbf*)(fbuf + FB_A1C);
    hbf*   A1r = (hbf*)(fbuf + FB_A1R);
    float* o1C = (float*)(fbuf + FB_O1C);
    float* o1R = (float*)(fbuf + FB_O1R);
    hbf*   SQL = A1c;
    hbf*   SQU = A1r;
    hbf*   s3c = (hbf*)(fbuf + FB_S3C);
    hbf*   s3r = (hbf*)(fbuf + FB_S3R);

    const int tid  = threadIdx.x;
    const int row0 = blockIdx.x * 16;
    const int b    = row0 / NF;
    const int f0   = row0 % NF;

    for (int c = tid; c < 16 * 256; c += 512) {
        const int m = c >> 8, i = c & 255;
        const int pos = (f0 + m) * STEPS + i;
        float l = 0.f, u = 0.f;
        if (pos < LEN) {
            l = lb[(size_t)b * LEN + pos];
            u = ub[(size_t)b * LEN + pos];
        }
        A1c[m * 272 + i] = __float2bfloat16(0.5f * (l + u));
        A1r[m * 272 + i] = __float2bfloat16(0.5f * (u - l));
    }
    __syncthreads();

    {
        const int w    = tid >> 6;
        const int lane = tid & 63;
        const int op   = w & 1;
        const int nh   = w >> 1;
        const int rc   = lane & 15;
        const int gk   = lane >> 4;
        const unsigned amask = op ? 0x7FFF7FFFu : 0xFFFFFFFFu;
        const hbf* ap = (op ? A1r : A1c) + rc * 272 + 8 * gk;
        float* outp = op ? o1R : o1C;
        const int nt0 = nh * 4, nt1 = (nh == 3) ? 17 : nh * 4 + 4;

        for (int nt = nt0; nt < nt1; ++nt) {
            f32x4 acc = {0.f, 0.f, 0.f, 0.f};
            const hbf* bp = Wt1f + (size_t)(nt * 16 + rc) * 256 + 8 * gk;
#pragma unroll
            for (int k0 = 0; k0 < 256; k0 += 32) {
                const bf16x8 afr = *(const bf16x8*)(ap + k0);
                union { bf16x8 v; unsigned u[4]; } t2;
                t2.v = *(const bf16x8*)(bp + k0);
                t2.u[0] &= amask; t2.u[1] &= amask;
                t2.u[2] &= amask; t2.u[3] &= amask;
                acc = __builtin_amdgcn_mfma_f32_16x16x32_bf16(afr, t2.v, acc, 0, 0, 0);
            }
            const int n = nt * 16 + rc;
#pragma unroll
            for (int reg = 0; reg < 4; ++reg)
                outp[(4 * gk + reg) * 272 + n] = acc[reg];
        }
    }
    __syncthreads();

    for (int c = tid; c < 16 * 258; c += 512) {
        const int m = c / 258, n = c - m * 258;
        const float oc = o1C[m * 272 + n];
        const float orr = o1R[m * 272 + n];
        const float l1l = oc - orr, l1u = oc + orr;
        const float a = l1l * l1l, bb = l1u * l1u;
        const float squ = fmaxf(a, bb);
        const float sql = (l1l <= 0.f && l1u >= 0.f) ? 0.f : fminf(a, bb);
        SQL[m * 272 + n] = __float2bfloat16(sql);
        SQU[m * 272 + n] = __float2bfloat16(squ);
    }
    __syncthreads();

    for (int idx = tid; idx < 16 * 64; idx += 512) {
        const int m = idx >> 6, n = idx & 63;
        float l2l = 1e-10f, l2u = 1e-10f;
#pragma unroll 2
        for (int i = 0; i < 258; ++i) {
            const float w = mtx2[i * NFILT + n];
            l2l = fmaf(__bfloat162float(SQL[m * 272 + i]), w, l2l);
            l2u = fmaf(__bfloat162float(SQU[m * 272 + i]), w, l2u);
        }
        const float lgl = logf(l2l);
        const float lgu = logf(l2u);
        s3c[m * 64 + n] = __float2bfloat16(0.5f * (lgl + lgu));
        s3r[m * 64 + n] = __float2bfloat16(0.5f * (lgu - lgl));
    }
    __syncthreads();

    {
        const int w    = tid >> 6;
        const int lane = tid & 63;
        const int rc   = lane & 15;
        const int gk   = lane >> 4;
        const hbf* apc = s3c + rc * 64 + 8 * gk;
        const hbf* apr = s3r + rc * 64 + 8 * gk;

        for (int nt = w * 4; nt < w * 4 + 4; ++nt) {
            f32x4 accC = {0.f, 0.f, 0.f, 0.f};
            f32x4 accR = {0.f, 0.f, 0.f, 0.f};
            const hbf* bp = Wt3f + (size_t)(nt * 16 + rc) * 64 + 8 * gk;
#pragma unroll
            for (int k0 = 0; k0 < 64; k0 += 32) {
                const bf16x8 ac = *(const bf16x8*)(apc + k0);
                const bf16x8 ar = *(const bf16x8*)(apr + k0);
                union { bf16x8 v; unsigned u[4]; } tw, ta;
                tw.v = *(const bf16x8*)(bp + k0);
                ta.v = tw.v;
                ta.u[0] &= 0x7FFF7FFFu; ta.u[1] &= 0x7FFF7FFFu;
                ta.u[2] &= 0x7FFF7FFFu; ta.u[3] &= 0x7FFF7FFFu;
                accC = __builtin_amdgcn_mfma_f32_16x16x32_bf16(ac, tw.v, accC, 0, 0, 0);
                accR = __builtin_amdgcn_mfma_f32_16x16x32_bf16(ar, ta.v, accR, 0, 0, 0);
            }
            const int n = nt * 16 + rc;
            const float bn = lin1_b[n];
#pragma unroll
            for (int reg = 0; reg < 4; ++reg) {
                const int m = 4 * gk + reg;
                const float oc = accC[reg] + bn;
                const float orr = accR[reg];
                const float n1l = oc - orr, n1u = oc + orr;
                const float rl = fmaxf(n1l, 0.f), ru = fmaxf(n1u, 0.f);
                const size_t o = ((size_t)(f0 + m) * BATCH + b) * HID + n;
                Xc[o] = __float2bfloat16(0.5f * (rl + ru));
                Xr[o] = __float2bfloat16(0.5f * (ru - rl));
            }
        }
    }
}

// ---------------------------------------------------------------------------
// One-time global barrier for registration (R7-proven).
// ---------------------------------------------------------------------------
__device__ __forceinline__ void gbar(unsigned* bar, unsigned gen,
                                     int bid, int tid) {
    __builtin_amdgcn_s_waitcnt(0);
    __syncthreads();
    if (bid == 0) {
        if (tid != 0) {
            while (ld_flag(&bar[ARV(tid)]) < gen)
                __builtin_amdgcn_s_sleep(1);
        }
        __syncthreads();
        if (tid < 8) st_flag(&bar[REL_(tid)], gen);
    } else {
        if (tid == 0) {
            st_flag(&bar[ARV(bid)], gen);
            while (ld_flag(&bar[REL_(bid & 7)]) < gen)
                __builtin_amdgcn_s_sleep(4);
        }
        asm volatile("" ::: "memory");
    }
    __syncthreads();
}

// ---------------------------------------------------------------------------
__device__ __forceinline__ void cell_elem(
    const float C[4], const float R[4], const float bs[4],
    float& cl_r, float& cu_r, float& nhl, float& nhu)
{
    float gl[4], gu[4];
#pragma unroll
    for (int g = 0; g < 4; ++g) {
        gl[g] = C[g] - R[g] + bs[g];
        gu[g] = C[g] + R[g] + bs[g];
    }
    const float il = fsig(gl[0]), iu = fsig(gu[0]);
    const float fl = fsig(gl[1]), fu = fsig(gu[1]);
    const float ggl = ftanh(gl[2]), ggu = ftanh(gu[2]);
    const float ol = fsig(gl[3]), ou = fsig(gu[3]);

    float fcl, fcu, igl, igu;
    imulf_(fl, fu, cl_r, cu_r, fcl, fcu);
    imulf_(il, iu, ggl, ggu, igl, igu);
    const float ncl = fcl + igl, ncu = fcu + igu;
    cl_r = ncl; cu_r = ncu;
    imulf_(ol, ou, ftanh(ncl), ftanh(ncu), nhl, nhu);
}

// GEMM over one K-half from LDS weights; MASKED is a literal 0/1.
#define GEMM_HALF(KBASE, MASKED)                                               \
    _Pragma("unroll")                                                          \
    for (int kk = 0; kk < 16; ++kk) {                                          \
        const int KK = (KBASE) + kk;                                           \
        _Pragma("unroll")                                                      \
        for (int g = 0; g < 4; ++g) {                                          \
            union { bf16x8 v; unsigned u[4]; } t2;                             \
            t2.v = *(const bf16x8*)&Wlds[(size_t)(((g << 5) | KK) * 64 + lane) * 8]; \
            if (MASKED) {                                                      \
                t2.u[0] &= 0x7FFF7FFFu; t2.u[1] &= 0x7FFF7FFFu;                \
                t2.u[2] &= 0x7FFF7FFFu; t2.u[3] &= 0x7FFF7FFFu;                \
            }                                                                  \
            acc[g] = __builtin_amdgcn_mfma_f32_16x16x32_bf16(af[kk], t2.v, acc[g], 0, 0, 0); \
        }                                                                      \
    }

#define LOADA16(PTR)                                                           \
    _Pragma("unroll")                                                          \
    for (int i = 0; i < 16; ++i) af[i] = *(const bf16x8*)((PTR) + 32 * i);

// single-lane poll of a per-group monotonic arrival counter
#define POLL_CNT(GID, TGT)                                                     \
    if (tid == 0) {                                                            \
        const unsigned* pp = &gcnt[(GID) * 16];                                \
        while ((int)ld_flag(pp) < (TGT)) __builtin_amdgcn_s_sleep(1);          \
    }                                                                          \
    __syncthreads();

// ---------------------------------------------------------------------------
// Persistent LSTM (R16 configuration, best verified).
// Fast path: group == one physical XCD; intra-group H via plain L2
// stores/loads (write-once addresses, counter-gated). L0 mirrors H into
// plain ring RP0 (own h-reads, L2-hit) and agent ring Ring0 (cross-XCD
// L0->L1). L1 recycles X as its plain ring. One monotonic agent counter per
// group. Slow path: R12-proven all-agent protocol.
// ---------------------------------------------------------------------------
__global__ __launch_bounds__(256, 1) void lstm_persistent(
    const hbf* Xc, const hbf* Xr,                       // aliased w/ Ring1
    hbf* Ring1C, hbf* Ring1R,                           // = Xc, Xr (fast path)
    const hbf* __restrict__ Wt0, const hbf* __restrict__ Wt1,
    const float* __restrict__ b0, const float* __restrict__ b1,
    hbf* __restrict__ Ring0C, hbf* __restrict__ Ring0R, // NF slots, agent
    hbf* __restrict__ RP0C, hbf* __restrict__ RP0R,     // NF slots, plain (may==Ring0)
    int useP0,
    const hbf* __restrict__ Zbuf,                       // HSLOT zeros
    hbf* __restrict__ H1c0, hbf* __restrict__ H1r0,
    hbf* __restrict__ H1c1, hbf* __restrict__ H1r1,
    float* __restrict__ h1l, float* __restrict__ h1u,
    unsigned* __restrict__ bar, unsigned* __restrict__ tkt,
    unsigned* __restrict__ gcnt)
{
    const int tid = threadIdx.x;
    const int bid = blockIdx.x;

    __shared__ unsigned s_info, s_map;
    __shared__ int s_fast;
    __shared__ hbf   Wlds[4 * 32 * 64 * 8];      // 128 KB
    __shared__ float red[2][2][4][64][4];        // 16 KB
    __shared__ unsigned short houtC[32][16], houtR[32][16];   // 2 KB

    // ---- registration: physical XCD + ticket ----
    if (tid == 0) {
        unsigned xcc;
        asm volatile("s_getreg_b32 %0, hwreg(HW_REG_XCC_ID)" : "=s"(xcc));
        xcc &= 7u;
        const unsigned slot = __hip_atomic_fetch_add(
            &tkt[xcc * 16], 1u, __ATOMIC_RELAXED, __HIP_MEMORY_SCOPE_AGENT);
        s_info = (xcc << 16) | slot;
    }
    gbar(bar, 1, bid, tid);
    if (tid == 0) {
        unsigned cnt[8]; bool ok = true;
        for (int y = 0; y < 8; ++y) {
            cnt[y] = ld_flag(&tkt[y * 16]);
            ok = ok && (cnt[y] == 32u);
        }
        const unsigned xcc = s_info >> 16, slot = s_info & 0xffffu;
        unsigned rank;
        if (ok) rank = xcc * 32u + slot;
        else { rank = slot; for (unsigned y = 0; y < xcc; ++y) rank += cnt[y]; }
        s_map = rank; s_fast = ok ? 1 : 0;
    }
    __syncthreads();

    const unsigned rank = s_map;
    const bool fast = (s_fast != 0);
    int layer, mgrp, jslot;
    if (fast) { layer = (rank >> 5) & 1; mgrp = rank >> 6; jslot = rank & 31; }
    else      { layer = rank >> 7; mgrp = (rank >> 5) & 3; jslot = rank & 31; }
    const int m0 = mgrp * 32;
    const int j0 = jslot * 16;
    const int gid  = layer * 4 + mgrp;       // own group counter
    const int pgid = mgrp;                   // partner L0 group counter
    const bool p0 = fast && (useP0 != 0);

    // ---- stage weight slice into LDS ----
    {
        const hbf* Wt = layer ? Wt1 : Wt0;
        for (int c = tid; c < 8192; c += 256) {
            const int g  = c >> 11;
            const int kk = (c >> 6) & 31;
            const int l6 = c & 63;
            const int n  = g * HID2 + j0 + (l6 & 15);
            const int k  = kk * 32 + (l6 >> 4) * 8;
            *(ulonglong2*)&Wlds[(size_t)c * 8] =
                *(const ulonglong2*)(Wt + (size_t)n * KTOT + k);
        }
    }

    const int w    = tid >> 6;
    const int lane = tid & 63;
    const int op   = w & 1;                  // 0 center, 1 radius
    const int mh   = w >> 1;                 // m-half
    const int rc   = lane & 15;
    const int gk   = lane >> 4;
    const int aoff = (m0 + mh * 16 + rc) * 512 + 8 * gk;

    hbf* H1cb[2] = { H1c0, H1c1 };
    hbf* H1rb[2] = { H1r0, H1r1 };

    // cell-phase constants
    const int mm  = tid >> 4;
    const int cj  = tid & 15;
    const int ll  = ((mm >> 2) << 4) | cj;
    const int rr  = mm & 3;
    const int idx0 = (m0 + mm) * HID2 + j0 + cj;
    const int idx1 = idx0 + 16 * HID2;
    const float* bias = layer ? b1 : b0;
    float bs[4];
#pragma unroll
    for (int g = 0; g < 4; ++g) bs[g] = bias[g * HID2 + j0 + cj];

    // coalesced-store constants (1 qword per thread)
    const int st_arr = tid >> 7;             // 0=C, 1=R
    const int st_row = (tid >> 2) & 31;
    const int st_q   = tid & 3;
    const size_t st_off = (size_t)(m0 + st_row) * 512 + j0 + st_q * 4;

    float cAl = 0.f, cAu = 0.f, cBl = 0.f, cBu = 0.f;

    __syncthreads();                         // Wlds ready

    // ---- L0: prologue X[0] prefetch into registers ----
    bf16x8 xf[16];
    if (layer == 0) {
        const hbf* p = (op ? Xr : Xc) + aoff;
        bf16x8* af = xf;
        LOADA16(p)
    }

    for (int t = 0; t < NF; ++t) {
        const int wslot = t & 1, rslot = wslot ^ 1;
        f32x4 acc[4] = {f32x4{0,0,0,0}, f32x4{0,0,0,0},
                        f32x4{0,0,0,0}, f32x4{0,0,0,0}};

        if (layer == 0) {
            // x-half on prefetched registers, then issue X[t+1] loads
            {
                bf16x8* af = xf;
                if (op) { GEMM_HALF(0, 1) } else { GEMM_HALF(0, 0) }
                const int tn = (t + 1 < NF) ? (t + 1) : t;
                const hbf* p = (op ? Xr : Xc) + (size_t)tn * HSLOT + aoff;
                LOADA16(p)
            }
            POLL_CNT(gid, 32 * t)
            // h-half: RP0[t-1] plain (L2-hit) in fast+P0, else Ring0[t-1]
            {
                const hbf* p;
                if (t == 0)       p = Zbuf + aoff;
                else if (p0)      p = (op ? RP0R : RP0C) + (size_t)(t - 1) * HSLOT + aoff;
                else              p = (op ? Ring0R : Ring0C) + (size_t)(t - 1) * HSLOT + aoff;
                bf16x8 af[16];
                LOADA16(p)
                if (op) { GEMM_HALF(16, 1) } else { GEMM_HALF(16, 0) }
            }
        } else {
            POLL_CNT(gid, 32 * t)
            // h-half on own H-ring — overlaps the wait on L0
            {
                bf16x8 af[16];
                if (fast) {
                    const hbf* p = (t == 0) ? (Zbuf + aoff)
                        : ((op ? (const hbf*)Ring1R : (const hbf*)Ring1C)
                           + (size_t)(t - 1) * HSLOT + aoff);
                    LOADA16(p)
                } else {
                    const hbf* p = (op ? H1rb[rslot] : H1cb[rslot]) + aoff;
#pragma unroll
                    for (int i = 0; i < 16; ++i) af[i] = loadA16_agent(p + 32 * i);
                }
                if (op) { GEMM_HALF(16, 1) } else { GEMM_HALF(16, 0) }
            }
            POLL_CNT(pgid, 32 * (t + 1))
            // x-half on Ring0[t] — plain cached (fresh address)
            {
                const hbf* p = (op ? Ring0R : Ring0C) + (size_t)t * HSLOT + aoff;
                bf16x8 af[16];
                LOADA16(p)
                if (op) { GEMM_HALF(0, 1) } else { GEMM_HALF(0, 0) }
            }
        }

        // ---- reduce C/R across waves via LDS ----
#pragma unroll
        for (int g = 0; g < 4; ++g)
            *((f32x4*)&red[op][mh][g][lane][0]) = acc[g];
        __syncthreads();

        // ---- cell: 2 elements per thread, stage into LDS ----
        {
            float C0[4], R0[4], C1[4], R1[4];
#pragma unroll
            for (int g = 0; g < 4; ++g) {
                C0[g] = red[0][0][g][ll][rr];
                R0[g] = red[1][0][g][ll][rr];
                C1[g] = red[0][1][g][ll][rr];
                R1[g] = red[1][1][g][ll][rr];
            }
            const bool writeF = (layer == 1) && (t == NF - 1);

            float nhl, nhu;
            cell_elem(C0, R0, bs, cAl, cAu, nhl, nhu);
            {
                const __hip_bfloat16 hc = __float2bfloat16(0.5f * (nhl + nhu));
                const __hip_bfloat16 hr = __float2bfloat16(0.5f * (nhu - nhl));
                houtC[mm][cj] = *(const unsigned short*)&hc;
                houtR[mm][cj] = *(const unsigned short*)&hr;
            }
            if (writeF) { h1l[idx0] = nhl; h1u[idx0] = nhu; }

            cell_elem(C1, R1, bs, cBl, cBu, nhl, nhu);
            {
                const __hip_bfloat16 hc = __float2bfloat16(0.5f * (nhl + nhu));
                const __hip_bfloat16 hr = __float2bfloat16(0.5f * (nhu - nhl));
                houtC[mm + 16][cj] = *(const unsigned short*)&hc;
                houtR[mm + 16][cj] = *(const unsigned short*)&hr;
            }
            if (writeF) { h1l[idx1] = nhl; h1u[idx1] = nhu; }
        }
        __syncthreads();

        // ---- coalesced publication: u64 per thread ----
        {
            const ull v = *(const ull*)
                &(st_arr ? houtR : houtC)[st_row][st_q * 4];
            if (layer == 0) {
                hbf* aC = Ring0C + (size_t)t * HSLOT;
                hbf* aR = Ring0R + (size_t)t * HSLOT;
                __hip_atomic_store((ull*)((st_arr ? aR : aC) + st_off), v,
                                   __ATOMIC_RELAXED, __HIP_MEMORY_SCOPE_AGENT);
                if (p0) {
                    hbf* pC = RP0C + (size_t)t * HSLOT;
                    hbf* pR = RP0R + (size_t)t * HSLOT;
                    *(ull*)((st_arr ? pR : pC) + st_off) = v;
                }
            } else if (fast) {
                hbf* pC = Ring1C + (size_t)t * HSLOT;
                hbf* pR = Ring1R + (size_t)t * HSLOT;
                *(ull*)((st_arr ? pR : pC) + st_off) = v;   // plain, same-XCD L2
            } else {
                hbf* dC = H1cb[wslot];
                hbf* dR = H1rb[wslot];
                __hip_atomic_store((ull*)((st_arr ? dR : dC) + st_off), v,
                                   __ATOMIC_RELAXED, __HIP_MEMORY_SCOPE_AGENT);
            }
        }

        // ---- arrive: drain, bump group counter ----
        __builtin_amdgcn_s_waitcnt(0);
        __syncthreads();
        if (tid == 0)
            __hip_atomic_fetch_add(&gcnt[gid * 16], 1u, __ATOMIC_RELAXED,
                                   __HIP_MEMORY_SCOPE_AGENT);
    }
}

// ---------------------------------------------------------------------------
__global__ __launch_bounds__(64) void final_kernel(
    const float* __restrict__ h1l, const float* __restrict__ h1u,
    const float* __restrict__ w, const float* __restrict__ bias,
    float* __restrict__ out)
{
    const int b = blockIdx.x;
    const int j = threadIdx.x;
    if (j < NOUT) {
        float oc = bias[j], orr = 0.f;
        for (int i = 0; i < HID2; ++i) {
            const float lo = h1l[(size_t)b * HID2 + i];
            const float hi = h1u[(size_t)b * HID2 + i];
            const float wv = w[i * NOUT + j];
            oc  = fmaf(0.5f * (lo + hi), wv, oc);
            orr = fmaf(0.5f * (hi - lo), fabsf(wv), orr);
        }
        out[b * NOUT + j] = oc - orr;
        out[BATCH * NOUT + b * NOUT + j] = oc + orr;
    }
}

// ---------------------------------------------------------------------------
extern "C" void kernel_launch(void* const* d_in, const int* in_sizes, int n_in,
                              void* d_out, int out_size, void* d_ws, size_t ws_size,
                              hipStream_t stream)
{
    const float* input_lb = (const float*)d_in[0];
    const float* input_ub = (const float*)d_in[1];
    const float* mtx1     = (const float*)d_in[2];
    const float* mtx2     = (const float*)d_in[3];
    const float* lin1_w   = (const float*)d_in[4];
    const float* lin1_b   = (const float*)d_in[5];
    const float* w_ih0    = (const float*)d_in[6];
    const float* w_hh0    = (const float*)d_in[7];
    const float* b0       = (const float*)d_in[8];
    const float* w_ih1    = (const float*)d_in[9];
    const float* w_hh1    = (const float*)d_in[10];
    const float* b1       = (const float*)d_in[11];
    const float* lin2_w   = (const float*)d_in[12];
    const float* lin2_b   = (const float*)d_in[13];
    float* out = (float*)d_out;

    char* ws = (char*)d_ws;
    size_t off = 0;
    hbf* Xc = (hbf*)(ws + off); off += (size_t)NF * HSLOT * 2;
    hbf* Xr = (hbf*)(ws + off); off += (size_t)NF * HSLOT * 2;
    hbf* Wt0 = (hbf*)(ws + off); off += (size_t)G4 * KTOT * 2;
    hbf* Wt1 = (hbf*)(ws + off); off += (size_t)G4 * KTOT * 2;
    hbf* Wt1f = (hbf*)(ws + off); off += (size_t)272 * 256 * 2;
    hbf* Wt3f = (hbf*)(ws + off); off += (size_t)512 * 64 * 2;
    hbf* Ring0C = (hbf*)(ws + off); off += (size_t)NF * HSLOT * 2;
    hbf* Ring0R = (hbf*)(ws + off); off += (size_t)NF * HSLOT * 2;

    // zeroed-every-launch region
    char* zbase = ws + off;
    hbf* Zbuf = (hbf*)(ws + off); off += (size_t)HSLOT * 2;
    hbf* H1c0 = (hbf*)(ws + off); off += (size_t)HSLOT * 2;
    hbf* H1r0 = (hbf*)(ws + off); off += (size_t)HSLOT * 2;
    hbf* H1c1 = (hbf*)(ws + off); off += (size_t)HSLOT * 2;
    hbf* H1r1 = (hbf*)(ws + off); off += (size_t)HSLOT * 2;
    unsigned* tkt  = (unsigned*)(ws + off); off += (size_t)8 * 16 * 4;
    unsigned* bar  = (unsigned*)(ws + off); off += (size_t)BAR_WORDS * 4;
    unsigned* gcnt = (unsigned*)(ws + off); off += (size_t)8 * 16 * 4;
    const size_t zbytes = (size_t)((ws + off) - zbase);
    float* h1l = (float*)(ws + off); off += (size_t)HSLOT * 4;
    float* h1u = (float*)(ws + off); off += (size_t)HSLOT * 4;

    // optional plain mirror ring for L0 (fast path) — only if ws has room
    hbf* RP0C = Ring0C;
    hbf* RP0R = Ring0R;
    int useP0 = 0;
    {
        const size_t need = (size_t)NF * HSLOT * 2 * 2;   // two rings
        if (off + need <= ws_size) {
            RP0C = (hbf*)(ws + off); off += (size_t)NF * HSLOT * 2;
            RP0R = (hbf*)(ws + off); off += (size_t)NF * HSLOT * 2;
            useP0 = 1;
        }
    }

    hipMemsetAsync(zbase, 0, zbytes, stream);

    {
        const dim3 pgrid(G4 / 32, KTOT / 32);
        prep_weights_kernel<<<pgrid, 256, 0, stream>>>(w_ih0, w_hh0, Wt0);
        prep_weights_kernel<<<pgrid, 256, 0, stream>>>(w_ih1, w_hh1, Wt1);
        prep_mtx1_kernel<<<dim3(9, 8), 256, 0, stream>>>(mtx1, Wt1f);
        prep_lin1_kernel<<<dim3(16, 2), 256, 0, stream>>>(lin1_w, Wt3f);
    }

    frontend3_kernel<<<(BATCH * NF) / 16, 512, 0, stream>>>(
        input_lb, input_ub, Wt1f, mtx2, Wt3f, lin1_b, Xc, Xr);

    lstm_persistent<<<NBLK, 256, 0, stream>>>(
        Xc, Xr, Xc, Xr, Wt0, Wt1, b0, b1,
        Ring0C, Ring0R, RP0C, RP0R, useP0, Zbuf,
        H1c0, H1r0, H1c1, H1r1,
        h1l, h1u, bar, tkt, gcnt);

    final_kernel<<<BATCH, 64, 0, stream>>>(h1l, h1u, lin2_w, lin2_b, out);
}